// Round 6
// baseline (67.879 us; speedup 1.0000x reference)
//
#include <hip/hip_runtime.h>
#include <math.h>

#define NN 8192
#define NPHI 32
#define ROWS 8
#define TPB 256   // 4 waves of 64

typedef int iv4 __attribute__((ext_vector_type(4)));

// packed[j] = (y0, y1, y2, sq_j) with y = nodes[j] * W_theta[:,0]
__global__ void prep_kernel(const float* __restrict__ nodes,
                            const float* __restrict__ W_theta,
                            float4* __restrict__ packed) {
    int j = blockIdx.x * blockDim.x + threadIdx.x;
    if (j >= NN) return;
    float w0 = W_theta[0], w1 = W_theta[1], w2 = W_theta[2];
    float y0 = nodes[3 * j + 0] * w0;
    float y1 = nodes[3 * j + 1] * w1;
    float y2 = nodes[3 * j + 2] * w2;
    float sq = y0 * y0 + y1 * y1 + y2 * y2;
    packed[j] = make_float4(y0, y1, y2, sq);
}

// Streaming body; LOAD differs only in cache policy (plain vs nontemporal).
#define LD_PLAIN(p) (*(p))
#define LD_NT(p)    __builtin_nontemporal_load(p)
#define BODY(LOAD)                                                          \
    for (int k = 0; k < iters; ++k) {                                       \
        const int j0 = qbase + k * 256 + lane * 4;                          \
        iv4 av[ROWS];                                                       \
        _Pragma("unroll")                                                   \
        for (int r = 0; r < ROWS; ++r) {                                    \
            const iv4* ap = (const iv4*)(adj + (size_t)(i0 + r) * NN + j0); \
            av[r] = LOAD(ap);                                               \
        }                                                                   \
        float4 p[4];                                                        \
        _Pragma("unroll")                                                   \
        for (int t = 0; t < 4; ++t) p[t] = packed[j0 + t];                  \
        _Pragma("unroll")                                                   \
        for (int r = 0; r < ROWS; ++r) {                                    \
            _Pragma("unroll")                                               \
            for (int t = 0; t < 4; ++t) {                                   \
                float d2 = fmaf(a[r], p[t].x,                               \
                            fmaf(b[r], p[t].y,                              \
                             fmaf(c[r], p[t].z, p[t].w)));                  \
                d2 = (av[r][t] > 0) ? d2 : -INFINITY;                       \
                m[r] = fmaxf(m[r], d2);                                     \
            }                                                               \
        }                                                                   \
    }

// MALL partition: 3/8 of blocks (96 MB of adjacency) load PLAIN and should
// stay Infinity-Cache-resident across graph replays; 5/8 load NT (streamed,
// no allocation) so they don't evict the resident set. Interleaved by block
// index so HBM- and L3-served traffic stay concurrent.
__launch_bounds__(TPB, 4)
__global__ void maxdist_kernel(const float* __restrict__ prev,
                               const int* __restrict__ adj,
                               const float* __restrict__ W_phi,
                               const float4* __restrict__ packed,
                               float* __restrict__ out) {
    const int tid  = threadIdx.x;
    const int lane = tid & 63;
    const int wave = tid >> 6;            // 0..3 -> j-quarter
    const int i0   = blockIdx.x * ROWS;

    float a[ROWS], b[ROWS], c[ROWS], s[ROWS], m[ROWS];
#pragma unroll
    for (int r = 0; r < ROWS; ++r) {
        float4 p = packed[i0 + r];
        a[r] = -2.0f * p.x;
        b[r] = -2.0f * p.y;
        c[r] = -2.0f * p.z;
        s[r] = p.w;
        m[r] = -INFINITY;   // running max of (sq_j - 2*dot); s_i added at the end
    }

    const int qbase = wave * (NN / 4);
    const int iters = (NN / 4) / (64 * 4);      // 8

    if ((blockIdx.x & 7) < 3) {
        BODY(LD_PLAIN)
    } else {
        BODY(LD_NT)
    }

    // wave-level max reduce
#pragma unroll
    for (int r = 0; r < ROWS; ++r) {
        float v = m[r];
#pragma unroll
        for (int off = 32; off > 0; off >>= 1)
            v = fmaxf(v, __shfl_xor(v, off, 64));
        m[r] = v;
    }

    __shared__ float red[4][ROWS];
    if (lane == 0) {
#pragma unroll
        for (int r = 0; r < ROWS; ++r) red[wave][r] = m[r];
    }

    float wp = (lane < NPHI) ? W_phi[lane] : 0.0f;
#pragma unroll
    for (int off = 32; off > 0; off >>= 1) wp += __shfl_xor(wp, off, 64);
    const float wmean = wp / (float)NPHI;

    __syncthreads();

    if (tid < ROWS) {
        const int r = tid;
        // max over waves of (sq_j - 2*dot); full d2 = s_i + that
        const float d2max = fmaxf(fmaxf(red[0][r], red[1][r]),
                                  fmaxf(red[2][r], red[3][r]));
        const int i = i0 + r;
        const float si = packed[i].w;
        float d2 = si + d2max;           // -inf if no neighbor
        d2 = fmaxf(d2, 0.0f);
        const float md = sqrtf(d2);
        out[i] = (prev[i] + md * wmean) * 0.5f;
    }
}

extern "C" void kernel_launch(void* const* d_in, const int* in_sizes, int n_in,
                              void* d_out, int out_size, void* d_ws, size_t ws_size,
                              hipStream_t stream) {
    const float* prev    = (const float*)d_in[0];
    const float* nodes   = (const float*)d_in[1];
    const int*   adj     = (const int*)d_in[2];
    const float* W_phi   = (const float*)d_in[3];
    const float* W_theta = (const float*)d_in[4];
    float* out = (float*)d_out;

    float4* packed = (float4*)d_ws;   // 128 KB

    prep_kernel<<<(NN + TPB - 1) / TPB, TPB, 0, stream>>>(nodes, W_theta, packed);

    maxdist_kernel<<<NN / ROWS, TPB, 0, stream>>>(prev, adj, W_phi, packed, out);
}

// Round 7
// 56.463 us; speedup vs baseline: 1.2022x; 1.2022x over previous
//
#include <hip/hip_runtime.h>
#include <math.h>

#define NN 8192
#define NPHI 32
#define ROWS 8
#define TPB 256   // 4 waves of 64

typedef int iv4 __attribute__((ext_vector_type(4)));

// Two layouts of the y-table:
//   linear[j]  = (y0,y1,y2,sq_j)                       (row constants, epilogue)
//   perm[...]  = same data, permuted inside each 256-j chunk so that the
//                stream's t-th load is lane-consecutive:
//                perm[(j>>8)*256 + 64*(j&3) + ((j&255)>>2)] = linear[j]
//                => load instr t: perm[chunkbase + 64t + lane] gives lane l
//                   exactly packed[chunkbase + 4l + t]. Fully coalesced.
__global__ void prep_kernel(const float* __restrict__ nodes,
                            const float* __restrict__ W_theta,
                            float4* __restrict__ linear,
                            float4* __restrict__ perm) {
    int j = blockIdx.x * blockDim.x + threadIdx.x;
    if (j >= NN) return;
    float w0 = W_theta[0], w1 = W_theta[1], w2 = W_theta[2];
    float y0 = nodes[3 * j + 0] * w0;
    float y1 = nodes[3 * j + 1] * w1;
    float y2 = nodes[3 * j + 2] * w2;
    float sq = y0 * y0 + y1 * y1 + y2 * y2;
    float4 v = make_float4(y0, y1, y2, sq);
    linear[j] = v;
    perm[(j & ~255) + 64 * (j & 3) + ((j & 255) >> 2)] = v;
}

__launch_bounds__(TPB, 4)
__global__ void maxdist_kernel(const float* __restrict__ prev,
                               const int* __restrict__ adj,
                               const float* __restrict__ W_phi,
                               const float4* __restrict__ linear,
                               const float4* __restrict__ perm,
                               float* __restrict__ out) {
    const int tid  = threadIdx.x;
    const int lane = tid & 63;
    const int wave = tid >> 6;            // 0..3 -> j-quarter
    const int i0   = blockIdx.x * ROWS;

    float a[ROWS], b[ROWS], c[ROWS], m[ROWS];
#pragma unroll
    for (int r = 0; r < ROWS; ++r) {
        float4 p = linear[i0 + r];
        a[r] = -2.0f * p.x;
        b[r] = -2.0f * p.y;
        c[r] = -2.0f * p.z;
        m[r] = -INFINITY;   // running max of (sq_j - 2*dot); s_i added at the end
    }

    const int qbase = wave * (NN / 4);
    const int iters = (NN / 4) / (64 * 4);      // 8

    for (int k = 0; k < iters; ++k) {
        const int cb = qbase + k * 256;          // 256-j chunk base
        const int j0 = cb + lane * 4;            // this lane's 4 adjacency j's

        // 8 adjacency int4 loads first: HBM misses start early
        iv4 av[ROWS];
#pragma unroll
        for (int r = 0; r < ROWS; ++r)
            av[r] = *(const iv4*)(adj + (size_t)(i0 + r) * NN + j0);

        // permuted y-table: lane-consecutive loads, lane l gets packed[cb+4l+t]
        float4 p[4];
#pragma unroll
        for (int t = 0; t < 4; ++t) p[t] = perm[cb + 64 * t + lane];

#pragma unroll
        for (int r = 0; r < ROWS; ++r) {
#pragma unroll
            for (int t = 0; t < 4; ++t) {
                // partial = sq_j - 2*(y_i . y_j); s_i added in epilogue
                float d2 = fmaf(a[r], p[t].x,
                            fmaf(b[r], p[t].y,
                             fmaf(c[r], p[t].z, p[t].w)));
                d2 = (av[r][t] > 0) ? d2 : -INFINITY;
                m[r] = fmaxf(m[r], d2);
            }
        }
    }

    // wave-level max reduce
#pragma unroll
    for (int r = 0; r < ROWS; ++r) {
        float v = m[r];
#pragma unroll
        for (int off = 32; off > 0; off >>= 1)
            v = fmaxf(v, __shfl_xor(v, off, 64));
        m[r] = v;
    }

    __shared__ float red[4][ROWS];
    if (lane == 0) {
#pragma unroll
        for (int r = 0; r < ROWS; ++r) red[wave][r] = m[r];
    }

    float wp = (lane < NPHI) ? W_phi[lane] : 0.0f;
#pragma unroll
    for (int off = 32; off > 0; off >>= 1) wp += __shfl_xor(wp, off, 64);
    const float wmean = wp / (float)NPHI;

    __syncthreads();

    if (tid < ROWS) {
        const int r = tid;
        const float d2max = fmaxf(fmaxf(red[0][r], red[1][r]),
                                  fmaxf(red[2][r], red[3][r]));
        const int i = i0 + r;
        const float si = linear[i].w;
        float d2 = si + d2max;           // -inf if no neighbor
        d2 = fmaxf(d2, 0.0f);
        const float md = sqrtf(d2);
        out[i] = (prev[i] + md * wmean) * 0.5f;
    }
}

extern "C" void kernel_launch(void* const* d_in, const int* in_sizes, int n_in,
                              void* d_out, int out_size, void* d_ws, size_t ws_size,
                              hipStream_t stream) {
    const float* prev    = (const float*)d_in[0];
    const float* nodes   = (const float*)d_in[1];
    const int*   adj     = (const int*)d_in[2];
    const float* W_phi   = (const float*)d_in[3];
    const float* W_theta = (const float*)d_in[4];
    float* out = (float*)d_out;

    float4* linear = (float4*)d_ws;                 // 128 KB
    float4* perm   = (float4*)d_ws + NN;            // 128 KB

    prep_kernel<<<(NN + TPB - 1) / TPB, TPB, 0, stream>>>(nodes, W_theta, linear, perm);

    maxdist_kernel<<<NN / ROWS, TPB, 0, stream>>>(prev, adj, W_phi, linear, perm, out);
}

// Round 8
// 55.916 us; speedup vs baseline: 1.2140x; 1.0098x over previous
//
#include <hip/hip_runtime.h>
#include <math.h>

#define NN 8192
#define NPHI 32
#define ROWS 8
#define TPB 256   // 4 waves of 64

typedef int iv4 __attribute__((ext_vector_type(4)));

// Two layouts of the y-table:
//   linear[j] = (y0,y1,y2,sq_j)
//   perm[...] = permuted inside each 256-j chunk so the stream's t-th load is
//               lane-consecutive: perm[(j&~255) + 64*(j&3) + ((j&255)>>2)]
__global__ void prep_kernel(const float* __restrict__ nodes,
                            const float* __restrict__ W_theta,
                            float4* __restrict__ linear,
                            float4* __restrict__ perm) {
    int j = blockIdx.x * blockDim.x + threadIdx.x;
    if (j >= NN) return;
    float w0 = W_theta[0], w1 = W_theta[1], w2 = W_theta[2];
    float y0 = nodes[3 * j + 0] * w0;
    float y1 = nodes[3 * j + 1] * w1;
    float y2 = nodes[3 * j + 2] * w2;
    float sq = y0 * y0 + y1 * y1 + y2 * y2;
    float4 v = make_float4(y0, y1, y2, sq);
    linear[j] = v;
    perm[(j & ~255) + 64 * (j & 3) + ((j & 255) >> 2)] = v;
}

// DRAM-burst layout: the block's 4 waves read ADJACENT 1 KB pieces of the
// same column window, so each row is touched in one contiguous 4 KB burst
// per iteration (32 cache lines), advancing 4 KB per iter. 8192 device-wide
// stream positions instead of 32768 -> better DRAM row-buffer locality.
__launch_bounds__(TPB, 4)
__global__ void maxdist_kernel(const float* __restrict__ prev,
                               const int* __restrict__ adj,
                               const float* __restrict__ W_phi,
                               const float4* __restrict__ linear,
                               const float4* __restrict__ perm,
                               float* __restrict__ out) {
    const int tid  = threadIdx.x;
    const int lane = tid & 63;
    const int wave = tid >> 6;
    const int i0   = blockIdx.x * ROWS;

    float a[ROWS], b[ROWS], c[ROWS], m[ROWS];
#pragma unroll
    for (int r = 0; r < ROWS; ++r) {
        float4 p = linear[i0 + r];
        a[r] = -2.0f * p.x;
        b[r] = -2.0f * p.y;
        c[r] = -2.0f * p.z;
        m[r] = -INFINITY;   // running max of (sq_j - 2*dot); s_i added at the end
    }

    const int iters = NN / 1024;                 // 8

    for (int k = 0; k < iters; ++k) {
        const int cb = k * 1024 + wave * 256;    // this wave's 256-j chunk
        const int j0 = cb + lane * 4;

        // 8 adjacency int4 loads first: HBM misses start early
        iv4 av[ROWS];
#pragma unroll
        for (int r = 0; r < ROWS; ++r)
            av[r] = *(const iv4*)(adj + (size_t)(i0 + r) * NN + j0);

        // permuted y-table: lane-consecutive, lane l gets packed[cb+4l+t]
        float4 p[4];
#pragma unroll
        for (int t = 0; t < 4; ++t) p[t] = perm[cb + 64 * t + lane];

#pragma unroll
        for (int r = 0; r < ROWS; ++r) {
#pragma unroll
            for (int t = 0; t < 4; ++t) {
                float d2 = fmaf(a[r], p[t].x,
                            fmaf(b[r], p[t].y,
                             fmaf(c[r], p[t].z, p[t].w)));
                d2 = (av[r][t] > 0) ? d2 : -INFINITY;
                m[r] = fmaxf(m[r], d2);
            }
        }
    }

    // wave-level max reduce
#pragma unroll
    for (int r = 0; r < ROWS; ++r) {
        float v = m[r];
#pragma unroll
        for (int off = 32; off > 0; off >>= 1)
            v = fmaxf(v, __shfl_xor(v, off, 64));
        m[r] = v;
    }

    __shared__ float red[4][ROWS];
    if (lane == 0) {
#pragma unroll
        for (int r = 0; r < ROWS; ++r) red[wave][r] = m[r];
    }

    float wp = (lane < NPHI) ? W_phi[lane] : 0.0f;
#pragma unroll
    for (int off = 32; off > 0; off >>= 1) wp += __shfl_xor(wp, off, 64);
    const float wmean = wp / (float)NPHI;

    __syncthreads();

    if (tid < ROWS) {
        const int r = tid;
        const float d2max = fmaxf(fmaxf(red[0][r], red[1][r]),
                                  fmaxf(red[2][r], red[3][r]));
        const int i = i0 + r;
        const float si = linear[i].w;
        float d2 = si + d2max;           // -inf if no neighbor
        d2 = fmaxf(d2, 0.0f);
        const float md = sqrtf(d2);
        out[i] = (prev[i] + md * wmean) * 0.5f;
    }
}

extern "C" void kernel_launch(void* const* d_in, const int* in_sizes, int n_in,
                              void* d_out, int out_size, void* d_ws, size_t ws_size,
                              hipStream_t stream) {
    const float* prev    = (const float*)d_in[0];
    const float* nodes   = (const float*)d_in[1];
    const int*   adj     = (const int*)d_in[2];
    const float* W_phi   = (const float*)d_in[3];
    const float* W_theta = (const float*)d_in[4];
    float* out = (float*)d_out;

    float4* linear = (float4*)d_ws;
    float4* perm   = (float4*)d_ws + NN;

    prep_kernel<<<(NN + TPB - 1) / TPB, TPB, 0, stream>>>(nodes, W_theta, linear, perm);

    maxdist_kernel<<<NN / ROWS, TPB, 0, stream>>>(prev, adj, W_phi, linear, perm, out);
}

// Round 9
// 53.367 us; speedup vs baseline: 1.2719x; 1.0478x over previous
//
#include <hip/hip_runtime.h>
#include <math.h>

#define NN 8192
#define NPHI 32
#define ROWS 4
#define TPB 256   // 4 waves of 64

typedef int iv4 __attribute__((ext_vector_type(4)));

// Two layouts of the y-table:
//   linear[j] = (y0,y1,y2,sq_j)
//   perm[...] = permuted inside each 256-j chunk so the stream's t-th load is
//               lane-consecutive: perm[(j&~255) + 64*(j&3) + ((j&255)>>2)]
__global__ void prep_kernel(const float* __restrict__ nodes,
                            const float* __restrict__ W_theta,
                            float4* __restrict__ linear,
                            float4* __restrict__ perm) {
    int j = blockIdx.x * blockDim.x + threadIdx.x;
    if (j >= NN) return;
    float w0 = W_theta[0], w1 = W_theta[1], w2 = W_theta[2];
    float y0 = nodes[3 * j + 0] * w0;
    float y1 = nodes[3 * j + 1] * w1;
    float y2 = nodes[3 * j + 2] * w2;
    float sq = y0 * y0 + y1 * y1 + y2 * y2;
    float4 v = make_float4(y0, y1, y2, sq);
    linear[j] = v;
    perm[(j & ~255) + 64 * (j & 3) + ((j & 255) >> 2)] = v;
}

// OCCUPANCY ISOLATION: ROWS=4 shrinks the live set to ~58 VGPR so
// __launch_bounds__(256,8) (VGPR cap 64) holds 32 waves/CU — double R8's
// TLP, doubling outstanding misses under loaded HBM latency.
// 2048 blocks = exactly 8 blocks/CU. Row bases are wave-uniform (SGPR path);
// lane voffset shared across the 4 row loads.
__launch_bounds__(TPB, 8)
__global__ void maxdist_kernel(const float* __restrict__ prev,
                               const int* __restrict__ adj,
                               const float* __restrict__ W_phi,
                               const float4* __restrict__ linear,
                               const float4* __restrict__ perm,
                               float* __restrict__ out) {
    const int tid  = threadIdx.x;
    const int lane = tid & 63;
    const int wave = tid >> 6;
    const int i0   = blockIdx.x * ROWS;

    float a[ROWS], b[ROWS], c[ROWS], m[ROWS];
#pragma unroll
    for (int r = 0; r < ROWS; ++r) {
        float4 p = linear[i0 + r];
        a[r] = -2.0f * p.x;
        b[r] = -2.0f * p.y;
        c[r] = -2.0f * p.z;
        m[r] = -INFINITY;   // running max of (sq_j - 2*dot); s_i added at the end
    }

    const int iters = NN / 1024;                 // 8

    for (int k = 0; k < iters; ++k) {
        const int cb = k * 1024 + wave * 256;    // this wave's 256-j chunk
        const int j0 = cb + lane * 4;

        // 4 adjacency int4 loads first (wave-uniform row base + lane voffset)
        iv4 av[ROWS];
#pragma unroll
        for (int r = 0; r < ROWS; ++r)
            av[r] = *(const iv4*)(adj + (size_t)(i0 + r) * NN + j0);

        // permuted y-table: lane-consecutive, lane l gets packed[cb+4l+t]
        float4 p[4];
#pragma unroll
        for (int t = 0; t < 4; ++t) p[t] = perm[cb + 64 * t + lane];

#pragma unroll
        for (int r = 0; r < ROWS; ++r) {
#pragma unroll
            for (int t = 0; t < 4; ++t) {
                float d2 = fmaf(a[r], p[t].x,
                            fmaf(b[r], p[t].y,
                             fmaf(c[r], p[t].z, p[t].w)));
                d2 = (av[r][t] > 0) ? d2 : -INFINITY;
                m[r] = fmaxf(m[r], d2);
            }
        }
    }

    // wave-level max reduce
#pragma unroll
    for (int r = 0; r < ROWS; ++r) {
        float v = m[r];
#pragma unroll
        for (int off = 32; off > 0; off >>= 1)
            v = fmaxf(v, __shfl_xor(v, off, 64));
        m[r] = v;
    }

    __shared__ float red[4][ROWS];
    if (lane == 0) {
#pragma unroll
        for (int r = 0; r < ROWS; ++r) red[wave][r] = m[r];
    }

    float wp = (lane < NPHI) ? W_phi[lane] : 0.0f;
#pragma unroll
    for (int off = 32; off > 0; off >>= 1) wp += __shfl_xor(wp, off, 64);
    const float wmean = wp / (float)NPHI;

    __syncthreads();

    if (tid < ROWS) {
        const int r = tid;
        const float d2max = fmaxf(fmaxf(red[0][r], red[1][r]),
                                  fmaxf(red[2][r], red[3][r]));
        const int i = i0 + r;
        const float si = linear[i].w;
        float d2 = si + d2max;           // -inf if no neighbor
        d2 = fmaxf(d2, 0.0f);
        const float md = sqrtf(d2);
        out[i] = (prev[i] + md * wmean) * 0.5f;
    }
}

extern "C" void kernel_launch(void* const* d_in, const int* in_sizes, int n_in,
                              void* d_out, int out_size, void* d_ws, size_t ws_size,
                              hipStream_t stream) {
    const float* prev    = (const float*)d_in[0];
    const float* nodes   = (const float*)d_in[1];
    const int*   adj     = (const int*)d_in[2];
    const float* W_phi   = (const float*)d_in[3];
    const float* W_theta = (const float*)d_in[4];
    float* out = (float*)d_out;

    float4* linear = (float4*)d_ws;
    float4* perm   = (float4*)d_ws + NN;

    prep_kernel<<<(NN + TPB - 1) / TPB, TPB, 0, stream>>>(nodes, W_theta, linear, perm);

    maxdist_kernel<<<NN / ROWS, TPB, 0, stream>>>(prev, adj, W_phi, linear, perm, out);
}

// Round 10
// 51.106 us; speedup vs baseline: 1.3282x; 1.0442x over previous
//
#include <hip/hip_runtime.h>
#include <math.h>

#define NN 8192
#define NPHI 32
#define ROWS 2
#define TPB 256   // 4 waves of 64

typedef int iv4 __attribute__((ext_vector_type(4)));

// Two layouts of the y-table:
//   linear[j] = (y0,y1,y2,sq_j)
//   perm[...] = permuted inside each 256-j chunk so the stream's t-th load is
//               lane-consecutive: perm[(j&~255) + 64*(j&3) + ((j&255)>>2)]
__global__ void prep_kernel(const float* __restrict__ nodes,
                            const float* __restrict__ W_theta,
                            float4* __restrict__ linear,
                            float4* __restrict__ perm) {
    int j = blockIdx.x * blockDim.x + threadIdx.x;
    if (j >= NN) return;
    float w0 = W_theta[0], w1 = W_theta[1], w2 = W_theta[2];
    float y0 = nodes[3 * j + 0] * w0;
    float y1 = nodes[3 * j + 1] * w1;
    float y2 = nodes[3 * j + 2] * w2;
    float sq = y0 * y0 + y1 * y1 + y2 * y2;
    float4 v = make_float4(y0, y1, y2, sq);
    linear[j] = v;
    perm[(j & ~255) + 64 * (j & 3) + ((j & 255) >> 2)] = v;
}

// MAX IN-FLIGHT CONFIG: ROWS=2 shrinks live set (~48 VGPR) so a two-chunk
// software pipeline fits the 64-VGPR cap of __launch_bounds__(256,8):
// 8 adjacency int4 loads in flight per wave x 32 waves/CU = 256 KB/CU,
// 2x R9. 4096 blocks = 16/CU.
__launch_bounds__(TPB, 8)
__global__ void maxdist_kernel(const float* __restrict__ prev,
                               const int* __restrict__ adj,
                               const float* __restrict__ W_phi,
                               const float4* __restrict__ linear,
                               const float4* __restrict__ perm,
                               float* __restrict__ out) {
    const int tid  = threadIdx.x;
    const int lane = tid & 63;
    const int wave = tid >> 6;
    const int i0   = blockIdx.x * ROWS;

    float a[ROWS], b[ROWS], c[ROWS], m[ROWS];
#pragma unroll
    for (int r = 0; r < ROWS; ++r) {
        float4 p = linear[i0 + r];
        a[r] = -2.0f * p.x;
        b[r] = -2.0f * p.y;
        c[r] = -2.0f * p.z;
        m[r] = -INFINITY;   // running max of (sq_j - 2*dot); s_i added at the end
    }

    const int woff = wave * 256 + lane * 4;      // lane's j-offset inside a 1KB k-chunk
    const int poff = wave * 256 + lane;          // lane's perm offset

    // two k-chunks per iteration; all 8 adjacency loads issued up front
    for (int k = 0; k < NN / 1024; k += 2) {
        const int cb0 = k * 1024;
        const int cb1 = cb0 + 1024;

        iv4 av0[ROWS], av1[ROWS];
#pragma unroll
        for (int r = 0; r < ROWS; ++r)
            av0[r] = *(const iv4*)(adj + (size_t)(i0 + r) * NN + cb0 + woff);
#pragma unroll
        for (int r = 0; r < ROWS; ++r)
            av1[r] = *(const iv4*)(adj + (size_t)(i0 + r) * NN + cb1 + woff);

        float4 p0[4];
#pragma unroll
        for (int t = 0; t < 4; ++t) p0[t] = perm[cb0 + poff + 64 * t];
#pragma unroll
        for (int r = 0; r < ROWS; ++r) {
#pragma unroll
            for (int t = 0; t < 4; ++t) {
                float d2 = fmaf(a[r], p0[t].x,
                            fmaf(b[r], p0[t].y,
                             fmaf(c[r], p0[t].z, p0[t].w)));
                d2 = (av0[r][t] > 0) ? d2 : -INFINITY;
                m[r] = fmaxf(m[r], d2);
            }
        }

        float4 p1[4];
#pragma unroll
        for (int t = 0; t < 4; ++t) p1[t] = perm[cb1 + poff + 64 * t];
#pragma unroll
        for (int r = 0; r < ROWS; ++r) {
#pragma unroll
            for (int t = 0; t < 4; ++t) {
                float d2 = fmaf(a[r], p1[t].x,
                            fmaf(b[r], p1[t].y,
                             fmaf(c[r], p1[t].z, p1[t].w)));
                d2 = (av1[r][t] > 0) ? d2 : -INFINITY;
                m[r] = fmaxf(m[r], d2);
            }
        }
    }

    // wave-level max reduce
#pragma unroll
    for (int r = 0; r < ROWS; ++r) {
        float v = m[r];
#pragma unroll
        for (int off = 32; off > 0; off >>= 1)
            v = fmaxf(v, __shfl_xor(v, off, 64));
        m[r] = v;
    }

    __shared__ float red[4][ROWS];
    if (lane == 0) {
#pragma unroll
        for (int r = 0; r < ROWS; ++r) red[wave][r] = m[r];
    }

    float wp = (lane < NPHI) ? W_phi[lane] : 0.0f;
#pragma unroll
    for (int off = 32; off > 0; off >>= 1) wp += __shfl_xor(wp, off, 64);
    const float wmean = wp / (float)NPHI;

    __syncthreads();

    if (tid < ROWS) {
        const int r = tid;
        const float d2max = fmaxf(fmaxf(red[0][r], red[1][r]),
                                  fmaxf(red[2][r], red[3][r]));
        const int i = i0 + r;
        const float si = linear[i].w;
        float d2 = si + d2max;           // -inf if no neighbor
        d2 = fmaxf(d2, 0.0f);
        const float md = sqrtf(d2);
        out[i] = (prev[i] + md * wmean) * 0.5f;
    }
}

extern "C" void kernel_launch(void* const* d_in, const int* in_sizes, int n_in,
                              void* d_out, int out_size, void* d_ws, size_t ws_size,
                              hipStream_t stream) {
    const float* prev    = (const float*)d_in[0];
    const float* nodes   = (const float*)d_in[1];
    const int*   adj     = (const int*)d_in[2];
    const float* W_phi   = (const float*)d_in[3];
    const float* W_theta = (const float*)d_in[4];
    float* out = (float*)d_out;

    float4* linear = (float4*)d_ws;
    float4* perm   = (float4*)d_ws + NN;

    prep_kernel<<<(NN + TPB - 1) / TPB, TPB, 0, stream>>>(nodes, W_theta, linear, perm);

    maxdist_kernel<<<NN / ROWS, TPB, 0, stream>>>(prev, adj, W_phi, linear, perm, out);
}